// Round 21
// baseline (233.027 us; speedup 1.0000x reference)
//
#include <hip/hip_runtime.h>
#include <cstddef>

// ---------------------------------------------------------------------------
// Mamba block forward. B=2, L=1024, D=1024, ED=2048, N=16, R=64, K=4. BL=2048.
// Round 21: BARRIER-FREE wave-private GEMM — each wave stages its own 64x64
// quadrant tiles into private LDS (double-buffered), ordered only by its own
// vmcnt/lgkmcnt. No s_barrier anywhere in the K-loop.
// ---------------------------------------------------------------------------

#define BL   2048
#define DIM  1024
#define ED   2048
#define NST  16
#define RLOW 64
#define CH   64
#define LC   16
#define SK   16        // K-splits for x_proj
#define DBCN 196608    // BL*96

typedef __attribute__((ext_vector_type(4))) float   f32x4;
typedef __attribute__((ext_vector_type(8))) __bf16  bf16x8;
typedef __attribute__((ext_vector_type(8))) unsigned short us8;

__device__ __forceinline__ float silu_(float x) {
  return x / (1.f + __expf(-x));
}

__device__ __forceinline__ float softplus_(float x) {
  const float v = __logf(1.f + __expf(x));
  return (x > 20.f) ? x : v;
}

__device__ __forceinline__ unsigned short f2b(float x) {
  union { float f; unsigned int u; } v; v.f = x;
  unsigned int r = v.u + 0x7FFFu + ((v.u >> 16) & 1u);   // RNE
  return (unsigned short)(r >> 16);
}

__device__ __forceinline__ float b2f(unsigned short u) {
  union { unsigned int i; float f; } v; v.i = (unsigned int)u << 16; return v.f;
}

__device__ __forceinline__ f32x4 mfma_bf16(us8 a, us8 b, f32x4 c) {
  return __builtin_amdgcn_mfma_f32_16x16x32_bf16(
      __builtin_bit_cast(bf16x8, a), __builtin_bit_cast(bf16x8, b), c, 0, 0, 0);
}

template <int N> __device__ __forceinline__ void vwaitN() {
  if constexpr (N == 0)      asm volatile("s_waitcnt vmcnt(0)" ::: "memory");
  else if constexpr (N == 6) asm volatile("s_waitcnt vmcnt(6)" ::: "memory");
  else if constexpr (N == 8) asm volatile("s_waitcnt vmcnt(8)" ::: "memory");
}

#define GLOAD_LDS16(gaddr, laddr)                                              \
  __builtin_amdgcn_global_load_lds(                                            \
      (const __attribute__((address_space(1))) unsigned int*)(gaddr),          \
      (__attribute__((address_space(3))) unsigned int*)(laddr), 16, 0, 0)

// ---------------- bf16 MFMA GEMM, wave-private dbuf, NO BARRIERS ------------
// C[M,N] = A[M,K]bf16 @ W[N,K]bf16^T (+bias). OBF: bf16 out else f32.
// ACT==1: softplus epilogue. SWZ==1: bijective XCD remap (nwg%8==0).
// 4 waves in 2x2; wave (wr,wc) owns quadrant (WM x WN), stages PRIVATE A/W
// tiles (2 buffers). LDS per wave-buffer: A = FMW 16-row groups of 1024 B
// (slot s = (row=s&15, kchunk=s>>4)); fragment read m = bufA + m*1024 +
// lane*16 (sequential). Stage issue j: lane fetches global row
// base+j*16+(lane&15), k-chunk (lane>>4)*8 -> dest bufbase + j*1024 (+lane*16
// HW). Ordering per wave only: vmcnt(VPS) keeps next stage in flight;
// lgkmcnt(0) drains ds_reads before the same buffer is re-staged.
template <int BM, int BN, int ACT, bool OBF, int SWZ>
__global__ __launch_bounds__(256) void gemm_bf16(
    const unsigned short* __restrict__ A,
    const unsigned short* __restrict__ W,
    const float* __restrict__ bias,
    void* __restrict__ Cp, int ldc, int Nout, int Kloop, int lda, int sstride)
{
  constexpr int BK  = 32;
  constexpr int WM  = BM / 2, WN = BN / 2;
  constexpr int FMW = WM / 16, FNW = WN / 16;
  constexpr int VPS = FMW + FNW;               // vmem issues per stage
  constexpr int AB  = WM * BK * 2;             // A bytes per wave-buffer
  constexpr int WBb = WN * BK * 2;
  constexpr int BUF = AB + WBb;
  __shared__ char smem[4 * 2 * BUF];

  const int tid  = threadIdx.x;
  const int w    = tid >> 6;
  const int lane = tid & 63;
  const int wr   = w >> 1, wc = w & 1;

  int bx = blockIdx.x, by = blockIdx.y;
  if (SWZ) {
    const int nwg  = gridDim.x * gridDim.y;
    const int flat = by * gridDim.x + bx;
    const int nid  = (flat & 7) * (nwg >> 3) + (flat >> 3);
    bx = nid % gridDim.x;
    by = nid / gridDim.x;
  }
  const int bm = bx * BM;
  const int bn = by * BN;
  const int kb = blockIdx.z * Kloop;

  f32x4 acc[FMW][FNW];
#pragma unroll
  for (int m = 0; m < FMW; ++m)
#pragma unroll
    for (int n = 0; n < FNW; ++n) acc[m][n] = (f32x4){0.f, 0.f, 0.f, 0.f};

  char* wbase = smem + w * 2 * BUF;
  const unsigned short* Ag =
      A + (size_t)(bm + wr * WM + (lane & 15)) * lda + kb + (lane >> 4) * 8;
  const unsigned short* Wg =
      W + (size_t)(bn + wc * WN + (lane & 15)) * lda + kb + (lane >> 4) * 8;

#define STAGE(bb, k0)                                                          \
  {                                                                            \
    char* dst = wbase + (bb) * BUF;                                            \
    _Pragma("unroll")                                                          \
    for (int j = 0; j < FMW; ++j)                                              \
      GLOAD_LDS16(Ag + (size_t)(j * 16) * lda + (k0), dst + j * 1024);         \
    _Pragma("unroll")                                                          \
    for (int j = 0; j < FNW; ++j)                                              \
      GLOAD_LDS16(Wg + (size_t)(j * 16) * lda + (k0), dst + AB + j * 1024);    \
  }

  const int NT = Kloop / BK;
  STAGE(0, 0);
  if (NT > 1) STAGE(1, BK);

  for (int t = 0; t < NT; ++t) {
    if (t + 1 < NT) vwaitN<VPS>();
    else            vwaitN<0>();
    __builtin_amdgcn_sched_barrier(0);

    const char* bufc = wbase + (t & 1) * BUF;
    us8 af[FMW], wf[FNW];
#pragma unroll
    for (int m = 0; m < FMW; ++m)
      af[m] = *(const us8*)(bufc + m * 1024 + lane * 16);
#pragma unroll
    for (int n = 0; n < FNW; ++n)
      wf[n] = *(const us8*)(bufc + AB + n * 1024 + lane * 16);
    asm volatile("s_waitcnt lgkmcnt(0)" ::: "memory");
    __builtin_amdgcn_sched_barrier(0);
    if (t + 2 < NT) STAGE(t & 1, (size_t)(t + 2) * BK);

#pragma unroll
    for (int m = 0; m < FMW; ++m)
#pragma unroll
      for (int n = 0; n < FNW; ++n)
        acc[m][n] = mfma_bf16(af[m], wf[n], acc[m][n]);
  }
#undef STAGE

  // C/D layout: col=lane&15, row=(lane>>4)*4+r  [m89-verified]
  const int rbase = (lane >> 4) * 4;
  float* Cf = (float*)Cp + (size_t)blockIdx.z * sstride;
#pragma unroll
  for (int m = 0; m < FMW; ++m) {
#pragma unroll
    for (int n = 0; n < FNW; ++n) {
      const int col = bn + wc * WN + n * 16 + (lane & 15);
      if (col < Nout) {
        const float bv = bias ? bias[col] : 0.f;
#pragma unroll
        for (int r = 0; r < 4; ++r) {
          const int row = bm + wr * WM + m * 16 + rbase + r;
          float v = acc[m][n][r] + bv;
          if (ACT == 1) v = softplus_(v);
          if (OBF) ((unsigned short*)Cp)[(size_t)row * ldc + col] = f2b(v);
          else     Cf[(size_t)row * ldc + col] = v;
        }
      }
    }
  }
}

// dbc = sum over SK split-K partials; also emit cols [0,64) as bf16 (dtA).
__global__ __launch_bounds__(256) void reduce_dbc_k(
    const float* __restrict__ par, float* __restrict__ dbc,
    unsigned short* __restrict__ dtA)
{
  const int i = blockIdx.x * 256 + threadIdx.x;   // DBCN/4 threads
  float4 s = ((const float4*)par)[i];
#pragma unroll
  for (int sk = 1; sk < SK; ++sk) {
    float4 v = ((const float4*)(par + (size_t)sk * DBCN))[i];
    s.x += v.x; s.y += v.y; s.z += v.z; s.w += v.w;
  }
  ((float4*)dbc)[i] = s;
  const int row = i / 24, c4 = i % 24;            // 24 float4 per 96-col row
  if (c4 < 16) {
    ushort4 o;
    o.x = f2b(s.x); o.y = f2b(s.y); o.z = f2b(s.z); o.w = f2b(s.w);
    ((ushort4*)(dtA + (size_t)row * 64))[c4] = o;
  }
}

// out = sum of 4 out_proj split-K partials, 2048x1024 f32
__global__ __launch_bounds__(256) void reduce_out_k(
    const float* __restrict__ par, float* __restrict__ out)
{
  const int i = blockIdx.x * 256 + threadIdx.x;   // 524288 threads
  float4 a = ((const float4*)par)[i];
#pragma unroll
  for (int k = 1; k < 4; ++k) {
    float4 b = ((const float4*)(par + (size_t)k * 2097152))[i];
    a.x += b.x; a.y += b.y; a.z += b.z; a.w += b.w;
  }
  ((float4*)out)[i] = a;
}

// ---------------- fused converts --------------------------------------------
__global__ __launch_bounds__(256) void cvt_all_k(
    const float* __restrict__ x, const float* __restrict__ inw,
    const float* __restrict__ ow, const float* __restrict__ xpw,
    const float* __restrict__ dtw,
    unsigned short* __restrict__ xb, unsigned short* __restrict__ iwb,
    unsigned short* __restrict__ owb, unsigned short* __restrict__ xpwb,
    unsigned short* __restrict__ dtwb)
{
  const int i = blockIdx.x * 256 + threadIdx.x;
  const float* src; unsigned short* dst; int j;
  if (i < 524288)       { src = x;   dst = xb;  j = i; }
  else if (i < 1572864) { src = inw; dst = iwb; j = i - 524288; }
  else if (i < 2097152) { src = ow;  dst = owb; j = i - 1572864; }
  else if (i < 2162688) {
    j = i - 2097152;                    // xpw pad path
    const int idx = j * 4;
    ushort4 o = {0, 0, 0, 0};
    if ((idx >> 11) < 96) {
      float4 v = *(const float4*)(xpw + idx);
      o.x = f2b(v.x); o.y = f2b(v.y); o.z = f2b(v.z); o.w = f2b(v.w);
    }
    *(ushort4*)(xpwb + idx) = o;
    return;
  } else                { src = dtw; dst = dtwb; j = i - 2162688; }
  float4 v = ((const float4*)src)[j];
  ushort4 o;
  o.x = f2b(v.x); o.y = f2b(v.y); o.z = f2b(v.z); o.w = f2b(v.w);
  ((ushort4*)dst)[j] = o;
}

// ---------------- conv + SiLU (bf16 in, bf16 out) ---------------------------
__global__ __launch_bounds__(256) void conv_silu_k(
    const unsigned short* __restrict__ xzb, const float* __restrict__ cw,
    const float* __restrict__ cb, unsigned short* __restrict__ xcb)
{
  const int idx = blockIdx.x * 256 + threadIdx.x;
  const int row = idx >> 9;
  const int e   = (idx & 511) * 4;
  const int l   = row & 1023;
  const unsigned short* base = xzb + (size_t)(row - l) * (2 * ED) + e;

  float4 cbv = *(const float4*)(cb + e);
  float a0 = cbv.x, a1 = cbv.y, a2 = cbv.z, a3 = cbv.w;
#pragma unroll
  for (int k = 0; k < 4; ++k) {
    const int ls = l - 3 + k;
    if (ls >= 0) {
      ushort4 u = *(const ushort4*)(base + (size_t)ls * (2 * ED));
      a0 += cw[(size_t)(e + 0) * 4 + k] * b2f(u.x);
      a1 += cw[(size_t)(e + 1) * 4 + k] * b2f(u.y);
      a2 += cw[(size_t)(e + 2) * 4 + k] * b2f(u.z);
      a3 += cw[(size_t)(e + 3) * 4 + k] * b2f(u.w);
    }
  }
  ushort4 o;
  o.x = f2b(silu_(a0)); o.y = f2b(silu_(a1));
  o.z = f2b(silu_(a2)); o.w = f2b(silu_(a3));
  *(ushort4*)(xcb + (size_t)row * ED + e) = o;
}

// ---------------- chunked selective scan (CH=64, LC=16) ---------------------
__global__ __launch_bounds__(256, 4) void scan_phase1(
    const unsigned short* __restrict__ dt, const unsigned short* __restrict__ xcb,
    const float* __restrict__ dbc, const float* __restrict__ A_log,
    float* __restrict__ aprod_o, float* __restrict__ bfin_o)
{
  const int g  = blockIdx.x * 256 + threadIdx.x;
  const int e  = g & (ED - 1);
  const int bc = g >> 11;
  const int b  = bc >> 6;
  const int c  = bc & (CH - 1);
  const size_t rowbase = (size_t)b * 1024 + (size_t)c * LC;

  __shared__ float4 sB[LC][4];
  if (threadIdx.x < LC * 4) {
    const int row = threadIdx.x >> 2, q = threadIdx.x & 3;
    sB[row][q] = ((const float4*)(dbc + (rowbase + row) * 96 + RLOW))[q];
  }
  __syncthreads();

  float Aen[NST];
  {
    const float4* Ap = (const float4*)(A_log + (size_t)e * NST);
#pragma unroll
    for (int q = 0; q < 4; ++q) {
      float4 v = Ap[q];
      Aen[q*4+0] = -__expf(v.x); Aen[q*4+1] = -__expf(v.y);
      Aen[q*4+2] = -__expf(v.z); Aen[q*4+3] = -__expf(v.w);
    }
  }

  float dtv[LC], dxv[LC];
#pragma unroll
  for (int i = 0; i < LC; ++i) dtv[i] = b2f(dt[(rowbase + i) * ED + e]);
#pragma unroll
  for (int i = 0; i < LC; ++i)
    dxv[i] = dtv[i] * b2f(xcb[(rowbase + i) * ED + e]);

  float h[NST], ap[NST];
#pragma unroll
  for (int n = 0; n < NST; ++n) { h[n] = 0.f; ap[n] = 1.f; }

  for (int i = 0; i < LC; ++i) {
    float Bv[NST];
#pragma unroll
    for (int q = 0; q < 4; ++q) {
      float4 v = sB[i][q];
      Bv[q*4+0]=v.x; Bv[q*4+1]=v.y; Bv[q*4+2]=v.z; Bv[q*4+3]=v.w;
    }
#pragma unroll
    for (int n = 0; n < NST; ++n) {
      const float dA = __expf(dtv[i] * Aen[n]);
      ap[n] *= dA;
      h[n] = fmaf(dA, h[n], dxv[i] * Bv[n]);
    }
  }

  const size_t obase = ((size_t)(b * ED + e) * CH + c) * NST;
  float4* ao = (float4*)(aprod_o + obase);
  float4* bo = (float4*)(bfin_o + obase);
#pragma unroll
  for (int q = 0; q < 4; ++q) {
    ao[q] = make_float4(ap[q*4+0], ap[q*4+1], ap[q*4+2], ap[q*4+3]);
    bo[q] = make_float4(h[q*4+0],  h[q*4+1],  h[q*4+2],  h[q*4+3]);
  }
}

__global__ __launch_bounds__(256) void scan_phase2(
    const float* __restrict__ aprod, float* __restrict__ bfin)
{
  const int be   = blockIdx.x * 4 + (threadIdx.x >> 6);
  const int lane = threadIdx.x & 63;
  const size_t base = (size_t)be * CH * NST;

  float Aa[NST], Bb[NST];
  {
    const float4* ap4 = (const float4*)(aprod + base);
    const float4* bp4 = (const float4*)(bfin + base);
#pragma unroll
    for (int q = 0; q < 4; ++q) {
      float4 v = ap4[lane * 4 + q];
      Aa[q*4+0]=v.x; Aa[q*4+1]=v.y; Aa[q*4+2]=v.z; Aa[q*4+3]=v.w;
      float4 w = bp4[lane * 4 + q];
      Bb[q*4+0]=w.x; Bb[q*4+1]=w.y; Bb[q*4+2]=w.z; Bb[q*4+3]=w.w;
    }
  }

#pragma unroll
  for (int d = 1; d < 64; d <<= 1) {
#pragma unroll
    for (int r = 0; r < NST; ++r) {
      const float aP = __shfl_up(Aa[r], d);
      const float bP = __shfl_up(Bb[r], d);
      if (lane >= d) {
        Bb[r] = fmaf(Aa[r], bP, Bb[r]);
        Aa[r] *= aP;
      }
    }
  }

#pragma unroll
  for (int r = 0; r < NST; ++r) {
    const float hs = __shfl_up(Bb[r], 1);
    Bb[r] = (lane == 0) ? 0.f : hs;
  }

  float4* ob4 = (float4*)(bfin + base);
#pragma unroll
  for (int q = 0; q < 4; ++q)
    ob4[lane * 4 + q] = make_float4(Bb[q*4+0], Bb[q*4+1], Bb[q*4+2], Bb[q*4+3]);
}

__global__ __launch_bounds__(256, 4) void scan_phase3(
    const unsigned short* __restrict__ dt, const unsigned short* __restrict__ xcb,
    const float* __restrict__ dbc, const float* __restrict__ A_log,
    const float* __restrict__ Dp, const unsigned short* __restrict__ xzb,
    const float* __restrict__ hst, unsigned short* __restrict__ ygb)
{
  const int g  = blockIdx.x * 256 + threadIdx.x;
  const int e  = g & (ED - 1);
  const int bc = g >> 11;
  const int b  = bc >> 6;
  const int c  = bc & (CH - 1);
  const size_t rowbase = (size_t)b * 1024 + (size_t)c * LC;

  __shared__ float4 sBC[LC][8];
  if (threadIdx.x < LC * 8) {
    const int row = threadIdx.x >> 3, q = threadIdx.x & 7;
    sBC[row][q] = ((const float4*)(dbc + (rowbase + row) * 96 + RLOW))[q];
  }
  __syncthreads();

  float Aen[NST];
  {
    const float4* Ap = (const float4*)(A_log + (size_t)e * NST);
#pragma unroll
    for (int q = 0; q < 4; ++q) {
      float4 v = Ap[q];
      Aen[q*4+0] = -__expf(v.x); Aen[q*4+1] = -__expf(v.y);
      Aen[q*4+2] = -__expf(v.z); Aen[q*4+3] = -__expf(v.w);
    }
  }

  float dtv[LC], xcv[LC];
#pragma unroll
  for (int i = 0; i < LC; ++i) dtv[i] = b2f(dt[(rowbase + i) * ED + e]);
#pragma unroll
  for (int i = 0; i < LC; ++i) xcv[i] = b2f(xcb[(rowbase + i) * ED + e]);

  float h[NST];
  {
    const float4* Hp = (const float4*)(hst + ((size_t)(b * ED + e) * CH + c) * NST);
#pragma unroll
    for (int q = 0; q < 4; ++q) {
      float4 v = Hp[q];
      h[q*4+0]=v.x; h[q*4+1]=v.y; h[q*4+2]=v.z; h[q*4+3]=v.w;
    }
  }

  const float De = Dp[e];
  for (int i = 0; i < LC; ++i) {
    const size_t rr = rowbase + i;
    float Bv[NST], Cv[NST];
#pragma unroll
    for (int q = 0; q < 4; ++q) {
      float4 v = sBC[i][q];
      Bv[q*4+0]=v.x; Bv[q*4+1]=v.y; Bv[q*4+2]=v.z; Bv[q*4+3]=v.w;
      float4 w = sBC[i][q + 4];
      Cv[q*4+0]=w.x; Cv[q*4+1]=w.y; Cv[q*4+2]=w.z; Cv[q*4+3]=w.w;
    }
    const float dx = dtv[i] * xcv[i];
    float y = 0.f;
#pragma unroll
    for (int n = 0; n < NST; ++n) {
      const float dA = __expf(dtv[i] * Aen[n]);
      h[n] = fmaf(dA, h[n], dx * Bv[n]);
      y = fmaf(Cv[n], h[n], y);
    }
    y = fmaf(De, xcv[i], y);
    const float zf = b2f(xzb[rr * (2 * ED) + ED + e]);
    ygb[rr * ED + e] = f2b(y * silu_(zf));
  }
}

extern "C" void kernel_launch(void* const* d_in, const int* in_sizes, int n_in,
                              void* d_out, int out_size, void* d_ws, size_t ws_size,
                              hipStream_t stream) {
  const float* x         = (const float*)d_in[0];
  const float* in_w      = (const float*)d_in[1];
  const float* in_b      = (const float*)d_in[2];
  const float* conv_w    = (const float*)d_in[3];
  const float* conv_b    = (const float*)d_in[4];
  const float* xproj_w   = (const float*)d_in[5];
  const float* dtproj_w  = (const float*)d_in[6];
  const float* dtproj_b  = (const float*)d_in[7];
  const float* A_log     = (const float*)d_in[8];
  const float* D_param   = (const float*)d_in[9];
  const float* outproj_w = (const float*)d_in[10];
  float* out = (float*)d_out;

  float* ws    = (float*)d_ws;
  float* dbc   = ws;                  //    196,608 f
  unsigned short* dtbu = (unsigned short*)(dbc + 196608);   // 4,194,304 us
  float* aprod = (float*)(dtbu + 4194304); //  4,194,304 f
  float* bfin  = aprod + 4194304;     //  4,194,304 f
  float* parx  = bfin  + 4194304;     //  3,145,728 f (SK*DBCN)
  unsigned short* xzb  = (unsigned short*)(parx + 3145728); // 8,388,608 us
  unsigned short* xb   = xzb  + 8388608;                    // 2,097,152 us
  unsigned short* iwb  = xb   + 2097152;                    // 4,194,304 us
  unsigned short* owb  = iwb  + 4194304;                    // 2,097,152 us
  unsigned short* xpwb = owb  + 2097152;                    //   262,144 us
  unsigned short* xcb  = xpwb + 262144;                     // 4,194,304 us
  unsigned short* ygb  = xcb  + 4194304;                    // 4,194,304 us
  unsigned short* dtA  = ygb  + 4194304;                    //   131,072 us
  unsigned short* dtwb = dtA  + 131072;                     //   131,072 us
  float* paro  = aprod;  // out_proj partials: 4 x 2,097,152 f = aprod+bfin
                         // (both dead after scan_phase3)

  const dim3 blk(256);

  // 0) all bf16 converts in one launch
  cvt_all_k<<<dim3(2195456 / 256), blk, 0, stream>>>(
      x, in_w, outproj_w, xproj_w, dtproj_w, xb, iwb, owb, xpwb, dtwb);

  // 1) xz = x @ in_proj_w^T + b  -> bf16 (2048 x 4096, K=1024), XCD-swizzled
  gemm_bf16<128, 128, 0, true, 1><<<dim3(BL / 128, 4096 / 128), blk, 0, stream>>>(
      xb, iwb, in_b, xzb, 2 * ED, 2 * ED, DIM, DIM, 0);

  // 2) xc = silu(conv(xz[:, :ED]) + cb) -> bf16
  conv_silu_k<<<dim3((BL * (ED / 4)) / 256), blk, 0, stream>>>(
      xzb, conv_w, conv_b, xcb);

  // 3) dbc = xc @ x_proj_w^T  (2048 x 96, K=2048), split-K x16 + reduce
  gemm_bf16<128, 128, 0, false, 0><<<dim3(BL / 128, 1, SK), blk, 0, stream>>>(
      xcb, xpwb, nullptr, parx, 96, 96, ED / SK, ED, DBCN);
  reduce_dbc_k<<<dim3(DBCN / 4 / 256), blk, 0, stream>>>(parx, dbc, dtA);

  // 4) dt = softplus(dtA @ dt_proj_w^T + dt_proj_b) -> bf16 (2048x2048, K=64)
  gemm_bf16<64, 128, 1, true, 0><<<dim3(BL / 64, ED / 128), blk, 0, stream>>>(
      dtA, dtwb, dtproj_b, dtbu, ED, ED, RLOW, RLOW, 0);

  // 5) chunked scan (CH=64, LC=16)
  scan_phase1<<<dim3((2 * CH * ED) / 256), blk, 0, stream>>>(
      dtbu, xcb, dbc, A_log, aprod, bfin);
  scan_phase2<<<dim3((2 * ED) / 4), blk, 0, stream>>>(aprod, bfin);
  scan_phase3<<<dim3((2 * CH * ED) / 256), blk, 0, stream>>>(
      dtbu, xcb, dbc, A_log, D_param, xzb, bfin, ygb);

  // 6) out = yg @ out_proj_w^T  (2048 x 1024, K=2048), split-K x4 + reduce
  gemm_bf16<128, 128, 0, false, 0><<<dim3(BL / 128, 1024 / 128, 4), blk, 0, stream>>>(
      ygb, owb, nullptr, paro, DIM, DIM, ED / 4, ED, 2097152);
  reduce_out_k<<<dim3(2097152 / 4 / 256), blk, 0, stream>>>(paro, out);
}

// Round 22
// 191.609 us; speedup vs baseline: 1.2162x; 1.2162x over previous
//
#include <hip/hip_runtime.h>
#include <cstddef>

// ---------------------------------------------------------------------------
// Mamba block forward. B=2, L=1024, D=1024, ED=2048, N=16, R=64, K=4. BL=2048.
// Round 22: revert to R20 (best verified: 191.87 us). R21's barrier-free
// wave-private GEMM regressed (depth-1 flight + per-wave lgkmcnt drain).
// ---------------------------------------------------------------------------

#define BL   2048
#define DIM  1024
#define ED   2048
#define NST  16
#define RLOW 64
#define CH   64
#define LC   16
#define SK   16        // K-splits for x_proj
#define DBCN 196608    // BL*96

typedef __attribute__((ext_vector_type(4))) float   f32x4;
typedef __attribute__((ext_vector_type(8))) __bf16  bf16x8;
typedef __attribute__((ext_vector_type(8))) unsigned short us8;

__device__ __forceinline__ float silu_(float x) {
  return x / (1.f + __expf(-x));
}

__device__ __forceinline__ float softplus_(float x) {
  const float v = __logf(1.f + __expf(x));
  return (x > 20.f) ? x : v;
}

__device__ __forceinline__ unsigned short f2b(float x) {
  union { float f; unsigned int u; } v; v.f = x;
  unsigned int r = v.u + 0x7FFFu + ((v.u >> 16) & 1u);   // RNE
  return (unsigned short)(r >> 16);
}

__device__ __forceinline__ float b2f(unsigned short u) {
  union { unsigned int i; float f; } v; v.i = (unsigned int)u << 16; return v.f;
}

__device__ __forceinline__ f32x4 mfma_bf16(us8 a, us8 b, f32x4 c) {
  return __builtin_amdgcn_mfma_f32_16x16x32_bf16(
      __builtin_bit_cast(bf16x8, a), __builtin_bit_cast(bf16x8, b), c, 0, 0, 0);
}

template <int N> __device__ __forceinline__ void vwaitN() {
  if constexpr (N == 0)      asm volatile("s_waitcnt vmcnt(0)" ::: "memory");
  else if constexpr (N == 3) asm volatile("s_waitcnt vmcnt(3)" ::: "memory");
  else if constexpr (N == 4) asm volatile("s_waitcnt vmcnt(4)" ::: "memory");
  else if constexpr (N == 6) asm volatile("s_waitcnt vmcnt(6)" ::: "memory");
  else if constexpr (N == 8) asm volatile("s_waitcnt vmcnt(8)" ::: "memory");
}

#define GLOAD_LDS16(gaddr, laddr)                                              \
  __builtin_amdgcn_global_load_lds(                                            \
      (const __attribute__((address_space(1))) unsigned int*)(gaddr),          \
      (__attribute__((address_space(3))) unsigned int*)(laddr), 16, 0, 0)

// ---------------- bf16 MFMA GEMM, 4-buffer 3-deep pipeline, BK=32 -----------
// C[M,N] = A[M,K]bf16 @ W[N,K]bf16^T (+bias). OBF: bf16 out else f32.
// ACT==1: softplus epilogue. SWZ==1: bijective XCD remap of (bx,by)
// (requires gridDim.x*gridDim.y % 8 == 0; z untouched).
// LDS tile: 16-row groups of 1024 B; slot s holds (row=s&15, kchunk=s>>4).
// Wave fragment read for group g = g*1024 + lane*16 (sequential, 0-conflict).
// Pipeline: stages 0..2 in prologue; iter t waits vmcnt(min(NT-1-t,2)*VPS),
// barrier, then issues stage t+3 into buf[(t+3)&3] (readers passed barrier).
template <int BM, int BN, int ACT, bool OBF, int SWZ>
__global__ __launch_bounds__(256) void gemm_bf16(
    const unsigned short* __restrict__ A,
    const unsigned short* __restrict__ W,
    const float* __restrict__ bias,
    void* __restrict__ Cp, int ldc, int Nout, int Kloop, int lda, int sstride)
{
  constexpr int BK     = 32;
  constexpr int FM     = BM / 32;
  constexpr int FN     = BN / 32;
  constexpr int NLA    = BM / 64;              // 4KB issues per A tile
  constexpr int NLW    = BN / 64;
  constexpr int VPS    = NLA + NLW;            // vmem ops per stage per wave
  constexpr int ABYTES = BM * BK * 2;
  constexpr int WBYTES = BN * BK * 2;
  __shared__ char smem[4 * (ABYTES + WBYTES)];

  const int tid  = threadIdx.x;
  const int w    = tid >> 6;
  const int lane = tid & 63;
  const int wr   = w >> 1, wc = w & 1;

  int bx = blockIdx.x, by = blockIdx.y;
  if (SWZ) {
    const int nwg  = gridDim.x * gridDim.y;
    const int flat = by * gridDim.x + bx;      // dispatch order (x fastest)
    const int nid  = (flat & 7) * (nwg >> 3) + (flat >> 3);
    bx = nid % gridDim.x;
    by = nid / gridDim.x;
  }
  const int bm   = bx * BM;
  const int bn   = by * BN;
  const int kb   = blockIdx.z * Kloop;

  f32x4 acc[FM][FN];
#pragma unroll
  for (int m = 0; m < FM; ++m)
#pragma unroll
    for (int n = 0; n < FN; ++n) acc[m][n] = (f32x4){0.f, 0.f, 0.f, 0.f};

  const int srow = (w << 4) | (lane & 15);     // row within 64-row issue
  const int kch  = lane >> 4;                  // 8-elem chunk 0..3
  const int wofs = w * 1024;                   // wave's LDS slice in an issue

  const unsigned short* Ag = A + (size_t)(bm + srow) * lda + kb + kch * 8;
  const unsigned short* Wg = W + (size_t)(bn + srow) * lda + kb + kch * 8;

#define STAGE(cur, k0)                                                         \
  {                                                                            \
    char* ab = smem + (cur) * (ABYTES + WBYTES);                               \
    char* wb = ab + ABYTES;                                                    \
    _Pragma("unroll")                                                          \
    for (int j = 0; j < NLA; ++j)                                              \
      GLOAD_LDS16(Ag + (size_t)(j * 64) * lda + (k0), ab + j * 4096 + wofs);   \
    _Pragma("unroll")                                                          \
    for (int j = 0; j < NLW; ++j)                                              \
      GLOAD_LDS16(Wg + (size_t)(j * 64) * lda + (k0), wb + j * 4096 + wofs);   \
  }

  const int NT = Kloop / BK;
  STAGE(0, 0);
  if (NT > 1) STAGE(1, BK);
  if (NT > 2) STAGE(2, 2 * BK);

  for (int t = 0; t < NT; ++t) {
    if (t <= NT - 3)      vwaitN<2 * VPS>();
    else if (t == NT - 2) vwaitN<VPS>();
    else                  vwaitN<0>();
    __builtin_amdgcn_sched_barrier(0);
    __builtin_amdgcn_s_barrier();
    __builtin_amdgcn_sched_barrier(0);
    if (t + 3 < NT) STAGE((t + 3) & 3, (size_t)(t + 3) * BK);

    const char* ab = smem + (t & 3) * (ABYTES + WBYTES);
    const char* wb = ab + ABYTES;
    us8 af[FM], wf[FN];
#pragma unroll
    for (int m = 0; m < FM; ++m)
      af[m] = *(const us8*)(ab + (wr * FM + m) * 1024 + lane * 16);
#pragma unroll
    for (int n = 0; n < FN; ++n)
      wf[n] = *(const us8*)(wb + (wc * FN + n) * 1024 + lane * 16);
#pragma unroll
    for (int m = 0; m < FM; ++m)
#pragma unroll
      for (int n = 0; n < FN; ++n)
        acc[m][n] = mfma_bf16(af[m], wf[n], acc[m][n]);
  }
#undef STAGE

  // C/D layout: col=lane&15, row=(lane>>4)*4+r  [m89-verified]
  const int rbase = (lane >> 4) * 4;
  float* Cf = (float*)Cp + (size_t)blockIdx.z * sstride;
#pragma unroll
  for (int m = 0; m < FM; ++m) {
#pragma unroll
    for (int n = 0; n < FN; ++n) {
      const int col = bn + wc * (BN / 2) + n * 16 + (lane & 15);
      if (col < Nout) {
        const float bv = bias ? bias[col] : 0.f;
#pragma unroll
        for (int r = 0; r < 4; ++r) {
          const int row = bm + wr * (BM / 2) + m * 16 + rbase + r;
          float v = acc[m][n][r] + bv;
          if (ACT == 1) v = softplus_(v);
          if (OBF) ((unsigned short*)Cp)[(size_t)row * ldc + col] = f2b(v);
          else     Cf[(size_t)row * ldc + col] = v;
        }
      }
    }
  }
}

// dbc = sum over SK split-K partials; also emit cols [0,64) as bf16 (dtA).
__global__ __launch_bounds__(256) void reduce_dbc_k(
    const float* __restrict__ par, float* __restrict__ dbc,
    unsigned short* __restrict__ dtA)
{
  const int i = blockIdx.x * 256 + threadIdx.x;   // DBCN/4 threads
  float4 s = ((const float4*)par)[i];
#pragma unroll
  for (int sk = 1; sk < SK; ++sk) {
    float4 v = ((const float4*)(par + (size_t)sk * DBCN))[i];
    s.x += v.x; s.y += v.y; s.z += v.z; s.w += v.w;
  }
  ((float4*)dbc)[i] = s;
  const int row = i / 24, c4 = i % 24;            // 24 float4 per 96-col row
  if (c4 < 16) {
    ushort4 o;
    o.x = f2b(s.x); o.y = f2b(s.y); o.z = f2b(s.z); o.w = f2b(s.w);
    ((ushort4*)(dtA + (size_t)row * 64))[c4] = o;
  }
}

// out = sum of 4 out_proj split-K partials, 2048x1024 f32
__global__ __launch_bounds__(256) void reduce_out_k(
    const float* __restrict__ par, float* __restrict__ out)
{
  const int i = blockIdx.x * 256 + threadIdx.x;   // 524288 threads
  float4 a = ((const float4*)par)[i];
#pragma unroll
  for (int k = 1; k < 4; ++k) {
    float4 b = ((const float4*)(par + (size_t)k * 2097152))[i];
    a.x += b.x; a.y += b.y; a.z += b.z; a.w += b.w;
  }
  ((float4*)out)[i] = a;
}

// ---------------- fused converts --------------------------------------------
__global__ __launch_bounds__(256) void cvt_all_k(
    const float* __restrict__ x, const float* __restrict__ inw,
    const float* __restrict__ ow, const float* __restrict__ xpw,
    const float* __restrict__ dtw,
    unsigned short* __restrict__ xb, unsigned short* __restrict__ iwb,
    unsigned short* __restrict__ owb, unsigned short* __restrict__ xpwb,
    unsigned short* __restrict__ dtwb)
{
  const int i = blockIdx.x * 256 + threadIdx.x;
  const float* src; unsigned short* dst; int j;
  if (i < 524288)       { src = x;   dst = xb;  j = i; }
  else if (i < 1572864) { src = inw; dst = iwb; j = i - 524288; }
  else if (i < 2097152) { src = ow;  dst = owb; j = i - 1572864; }
  else if (i < 2162688) {
    j = i - 2097152;                    // xpw pad path
    const int idx = j * 4;
    ushort4 o = {0, 0, 0, 0};
    if ((idx >> 11) < 96) {
      float4 v = *(const float4*)(xpw + idx);
      o.x = f2b(v.x); o.y = f2b(v.y); o.z = f2b(v.z); o.w = f2b(v.w);
    }
    *(ushort4*)(xpwb + idx) = o;
    return;
  } else                { src = dtw; dst = dtwb; j = i - 2162688; }
  float4 v = ((const float4*)src)[j];
  ushort4 o;
  o.x = f2b(v.x); o.y = f2b(v.y); o.z = f2b(v.z); o.w = f2b(v.w);
  ((ushort4*)dst)[j] = o;
}

// ---------------- conv + SiLU (bf16 in, bf16 out) ---------------------------
__global__ __launch_bounds__(256) void conv_silu_k(
    const unsigned short* __restrict__ xzb, const float* __restrict__ cw,
    const float* __restrict__ cb, unsigned short* __restrict__ xcb)
{
  const int idx = blockIdx.x * 256 + threadIdx.x;
  const int row = idx >> 9;
  const int e   = (idx & 511) * 4;
  const int l   = row & 1023;
  const unsigned short* base = xzb + (size_t)(row - l) * (2 * ED) + e;

  float4 cbv = *(const float4*)(cb + e);
  float a0 = cbv.x, a1 = cbv.y, a2 = cbv.z, a3 = cbv.w;
#pragma unroll
  for (int k = 0; k < 4; ++k) {
    const int ls = l - 3 + k;
    if (ls >= 0) {
      ushort4 u = *(const ushort4*)(base + (size_t)ls * (2 * ED));
      a0 += cw[(size_t)(e + 0) * 4 + k] * b2f(u.x);
      a1 += cw[(size_t)(e + 1) * 4 + k] * b2f(u.y);
      a2 += cw[(size_t)(e + 2) * 4 + k] * b2f(u.z);
      a3 += cw[(size_t)(e + 3) * 4 + k] * b2f(u.w);
    }
  }
  ushort4 o;
  o.x = f2b(silu_(a0)); o.y = f2b(silu_(a1));
  o.z = f2b(silu_(a2)); o.w = f2b(silu_(a3));
  *(ushort4*)(xcb + (size_t)row * ED + e) = o;
}

// ---------------- chunked selective scan (CH=64, LC=16) ---------------------
__global__ __launch_bounds__(256, 4) void scan_phase1(
    const unsigned short* __restrict__ dt, const unsigned short* __restrict__ xcb,
    const float* __restrict__ dbc, const float* __restrict__ A_log,
    float* __restrict__ aprod_o, float* __restrict__ bfin_o)
{
  const int g  = blockIdx.x * 256 + threadIdx.x;
  const int e  = g & (ED - 1);
  const int bc = g >> 11;
  const int b  = bc >> 6;
  const int c  = bc & (CH - 1);
  const size_t rowbase = (size_t)b * 1024 + (size_t)c * LC;

  __shared__ float4 sB[LC][4];
  if (threadIdx.x < LC * 4) {
    const int row = threadIdx.x >> 2, q = threadIdx.x & 3;
    sB[row][q] = ((const float4*)(dbc + (rowbase + row) * 96 + RLOW))[q];
  }
  __syncthreads();

  float Aen[NST];
  {
    const float4* Ap = (const float4*)(A_log + (size_t)e * NST);
#pragma unroll
    for (int q = 0; q < 4; ++q) {
      float4 v = Ap[q];
      Aen[q*4+0] = -__expf(v.x); Aen[q*4+1] = -__expf(v.y);
      Aen[q*4+2] = -__expf(v.z); Aen[q*4+3] = -__expf(v.w);
    }
  }

  float dtv[LC], dxv[LC];
#pragma unroll
  for (int i = 0; i < LC; ++i) dtv[i] = b2f(dt[(rowbase + i) * ED + e]);
#pragma unroll
  for (int i = 0; i < LC; ++i)
    dxv[i] = dtv[i] * b2f(xcb[(rowbase + i) * ED + e]);

  float h[NST], ap[NST];
#pragma unroll
  for (int n = 0; n < NST; ++n) { h[n] = 0.f; ap[n] = 1.f; }

  for (int i = 0; i < LC; ++i) {
    float Bv[NST];
#pragma unroll
    for (int q = 0; q < 4; ++q) {
      float4 v = sB[i][q];
      Bv[q*4+0]=v.x; Bv[q*4+1]=v.y; Bv[q*4+2]=v.z; Bv[q*4+3]=v.w;
    }
#pragma unroll
    for (int n = 0; n < NST; ++n) {
      const float dA = __expf(dtv[i] * Aen[n]);
      ap[n] *= dA;
      h[n] = fmaf(dA, h[n], dxv[i] * Bv[n]);
    }
  }

  const size_t obase = ((size_t)(b * ED + e) * CH + c) * NST;
  float4* ao = (float4*)(aprod_o + obase);
  float4* bo = (float4*)(bfin_o + obase);
#pragma unroll
  for (int q = 0; q < 4; ++q) {
    ao[q] = make_float4(ap[q*4+0], ap[q*4+1], ap[q*4+2], ap[q*4+3]);
    bo[q] = make_float4(h[q*4+0],  h[q*4+1],  h[q*4+2],  h[q*4+3]);
  }
}

__global__ __launch_bounds__(256) void scan_phase2(
    const float* __restrict__ aprod, float* __restrict__ bfin)
{
  const int be   = blockIdx.x * 4 + (threadIdx.x >> 6);
  const int lane = threadIdx.x & 63;
  const size_t base = (size_t)be * CH * NST;

  float Aa[NST], Bb[NST];
  {
    const float4* ap4 = (const float4*)(aprod + base);
    const float4* bp4 = (const float4*)(bfin + base);
#pragma unroll
    for (int q = 0; q < 4; ++q) {
      float4 v = ap4[lane * 4 + q];
      Aa[q*4+0]=v.x; Aa[q*4+1]=v.y; Aa[q*4+2]=v.z; Aa[q*4+3]=v.w;
      float4 w = bp4[lane * 4 + q];
      Bb[q*4+0]=w.x; Bb[q*4+1]=w.y; Bb[q*4+2]=w.z; Bb[q*4+3]=w.w;
    }
  }

#pragma unroll
  for (int d = 1; d < 64; d <<= 1) {
#pragma unroll
    for (int r = 0; r < NST; ++r) {
      const float aP = __shfl_up(Aa[r], d);
      const float bP = __shfl_up(Bb[r], d);
      if (lane >= d) {
        Bb[r] = fmaf(Aa[r], bP, Bb[r]);
        Aa[r] *= aP;
      }
    }
  }

#pragma unroll
  for (int r = 0; r < NST; ++r) {
    const float hs = __shfl_up(Bb[r], 1);
    Bb[r] = (lane == 0) ? 0.f : hs;
  }

  float4* ob4 = (float4*)(bfin + base);
#pragma unroll
  for (int q = 0; q < 4; ++q)
    ob4[lane * 4 + q] = make_float4(Bb[q*4+0], Bb[q*4+1], Bb[q*4+2], Bb[q*4+3]);
}

__global__ __launch_bounds__(256, 4) void scan_phase3(
    const unsigned short* __restrict__ dt, const unsigned short* __restrict__ xcb,
    const float* __restrict__ dbc, const float* __restrict__ A_log,
    const float* __restrict__ Dp, const unsigned short* __restrict__ xzb,
    const float* __restrict__ hst, unsigned short* __restrict__ ygb)
{
  const int g  = blockIdx.x * 256 + threadIdx.x;
  const int e  = g & (ED - 1);
  const int bc = g >> 11;
  const int b  = bc >> 6;
  const int c  = bc & (CH - 1);
  const size_t rowbase = (size_t)b * 1024 + (size_t)c * LC;

  __shared__ float4 sBC[LC][8];
  if (threadIdx.x < LC * 8) {
    const int row = threadIdx.x >> 3, q = threadIdx.x & 7;
    sBC[row][q] = ((const float4*)(dbc + (rowbase + row) * 96 + RLOW))[q];
  }
  __syncthreads();

  float Aen[NST];
  {
    const float4* Ap = (const float4*)(A_log + (size_t)e * NST);
#pragma unroll
    for (int q = 0; q < 4; ++q) {
      float4 v = Ap[q];
      Aen[q*4+0] = -__expf(v.x); Aen[q*4+1] = -__expf(v.y);
      Aen[q*4+2] = -__expf(v.z); Aen[q*4+3] = -__expf(v.w);
    }
  }

  float dtv[LC], xcv[LC];
#pragma unroll
  for (int i = 0; i < LC; ++i) dtv[i] = b2f(dt[(rowbase + i) * ED + e]);
#pragma unroll
  for (int i = 0; i < LC; ++i) xcv[i] = b2f(xcb[(rowbase + i) * ED + e]);

  float h[NST];
  {
    const float4* Hp = (const float4*)(hst + ((size_t)(b * ED + e) * CH + c) * NST);
#pragma unroll
    for (int q = 0; q < 4; ++q) {
      float4 v = Hp[q];
      h[q*4+0]=v.x; h[q*4+1]=v.y; h[q*4+2]=v.z; h[q*4+3]=v.w;
    }
  }

  const float De = Dp[e];
  for (int i = 0; i < LC; ++i) {
    const size_t rr = rowbase + i;
    float Bv[NST], Cv[NST];
#pragma unroll
    for (int q = 0; q < 4; ++q) {
      float4 v = sBC[i][q];
      Bv[q*4+0]=v.x; Bv[q*4+1]=v.y; Bv[q*4+2]=v.z; Bv[q*4+3]=v.w;
      float4 w = sBC[i][q + 4];
      Cv[q*4+0]=w.x; Cv[q*4+1]=w.y; Cv[q*4+2]=w.z; Cv[q*4+3]=w.w;
    }
    const float dx = dtv[i] * xcv[i];
    float y = 0.f;
#pragma unroll
    for (int n = 0; n < NST; ++n) {
      const float dA = __expf(dtv[i] * Aen[n]);
      h[n] = fmaf(dA, h[n], dx * Bv[n]);
      y = fmaf(Cv[n], h[n], y);
    }
    y = fmaf(De, xcv[i], y);
    const float zf = b2f(xzb[rr * (2 * ED) + ED + e]);
    ygb[rr * ED + e] = f2b(y * silu_(zf));
  }
}

extern "C" void kernel_launch(void* const* d_in, const int* in_sizes, int n_in,
                              void* d_out, int out_size, void* d_ws, size_t ws_size,
                              hipStream_t stream) {
  const float* x         = (const float*)d_in[0];
  const float* in_w      = (const float*)d_in[1];
  const float* in_b      = (const float*)d_in[2];
  const float* conv_w    = (const float*)d_in[3];
  const float* conv_b    = (const float*)d_in[4];
  const float* xproj_w   = (const float*)d_in[5];
  const float* dtproj_w  = (const float*)d_in[6];
  const float* dtproj_b  = (const float*)d_in[7];
  const float* A_log     = (const float*)d_in[8];
  const float* D_param   = (const float*)d_in[9];
  const float* outproj_w = (const float*)d_in[10];
  float* out = (float*)d_out;

  float* ws    = (float*)d_ws;
  float* dbc   = ws;                  //    196,608 f
  unsigned short* dtbu = (unsigned short*)(dbc + 196608);   // 4,194,304 us
  float* aprod = (float*)(dtbu + 4194304); //  4,194,304 f
  float* bfin  = aprod + 4194304;     //  4,194,304 f
  float* parx  = bfin  + 4194304;     //  3,145,728 f (SK*DBCN)
  unsigned short* xzb  = (unsigned short*)(parx + 3145728); // 8,388,608 us
  unsigned short* xb   = xzb  + 8388608;                    // 2,097,152 us
  unsigned short* iwb  = xb   + 2097152;                    // 4,194,304 us
  unsigned short* owb  = iwb  + 4194304;                    // 2,097,152 us
  unsigned short* xpwb = owb  + 2097152;                    //   262,144 us
  unsigned short* xcb  = xpwb + 262144;                     // 4,194,304 us
  unsigned short* ygb  = xcb  + 4194304;                    // 4,194,304 us
  unsigned short* dtA  = ygb  + 4194304;                    //   131,072 us
  unsigned short* dtwb = dtA  + 131072;                     //   131,072 us
  float* paro  = aprod;  // out_proj partials: 4 x 2,097,152 f = aprod+bfin
                         // (both dead after scan_phase3)

  const dim3 blk(256);

  // 0) all bf16 converts in one launch
  cvt_all_k<<<dim3(2195456 / 256), blk, 0, stream>>>(
      x, in_w, outproj_w, xproj_w, dtproj_w, xb, iwb, owb, xpwb, dtwb);

  // 1) xz = x @ in_proj_w^T + b  -> bf16 (2048 x 4096, K=1024), XCD-swizzled
  gemm_bf16<128, 128, 0, true, 1><<<dim3(BL / 128, 4096 / 128), blk, 0, stream>>>(
      xb, iwb, in_b, xzb, 2 * ED, 2 * ED, DIM, DIM, 0);

  // 2) xc = silu(conv(xz[:, :ED]) + cb) -> bf16
  conv_silu_k<<<dim3((BL * (ED / 4)) / 256), blk, 0, stream>>>(
      xzb, conv_w, conv_b, xcb);

  // 3) dbc = xc @ x_proj_w^T  (2048 x 96, K=2048), split-K x16 + reduce
  gemm_bf16<128, 128, 0, false, 0><<<dim3(BL / 128, 1, SK), blk, 0, stream>>>(
      xcb, xpwb, nullptr, parx, 96, 96, ED / SK, ED, DBCN);
  reduce_dbc_k<<<dim3(DBCN / 4 / 256), blk, 0, stream>>>(parx, dbc, dtA);

  // 4) dt = softplus(dtA @ dt_proj_w^T + dt_proj_b) -> bf16 (2048x2048, K=64)
  gemm_bf16<64, 128, 1, true, 0><<<dim3(BL / 64, ED / 128), blk, 0, stream>>>(
      dtA, dtwb, dtproj_b, dtbu, ED, ED, RLOW, RLOW, 0);

  // 5) chunked scan (CH=64, LC=16)
  scan_phase1<<<dim3((2 * CH * ED) / 256), blk, 0, stream>>>(
      dtbu, xcb, dbc, A_log, aprod, bfin);
  scan_phase2<<<dim3((2 * ED) / 4), blk, 0, stream>>>(aprod, bfin);
  scan_phase3<<<dim3((2 * CH * ED) / 256), blk, 0, stream>>>(
      dtbu, xcb, dbc, A_log, D_param, xzb, bfin, ygb);

  // 6) out = yg @ out_proj_w^T  (2048 x 1024, K=2048), split-K x4 + reduce
  gemm_bf16<128, 128, 0, false, 0><<<dim3(BL / 128, 1024 / 128, 4), blk, 0, stream>>>(
      ygb, owb, nullptr, paro, DIM, DIM, ED / 4, ED, 2097152);
  reduce_out_k<<<dim3(2097152 / 4 / 256), blk, 0, stream>>>(paro, out);
}